// Round 1
// baseline (163.108 us; speedup 1.0000x reference)
//
#include <hip/hip_runtime.h>
#include <cmath>

// PositionIntervalLoss: B=65536 rows, F=300.
// One wave (64 lanes) per row, 4 rows per 256-thread block.

constexpr int FLEN = 300;
constexpr int RPB  = 4;    // rows per block (one wave each)

__global__ __launch_bounds__(256, 8)
void pil_kernel(const float* __restrict__ in, float* __restrict__ out,
                double bk0, double bk1, double bk2, double bk3)
{
    const int w    = threadIdx.x >> 6;   // wave index in block
    const int lane = threadIdx.x & 63;
    const int row  = blockIdx.x * RPB + w;

    // Per-row LDS workspaces (~14.3 KB/block total)
    __shared__ float rawp[RPB][308];   // [0..2]=0 pad, [3..302]=raw, [303..305]=0 pad
    __shared__ float fpad[RPB][304];   // [0]=-inf, [1..300]=blurred f, [301]=-inf
    __shared__ int   pos [RPB][152];   // sorted peak positions
    __shared__ int   bnd [RPB][152];   // segment boundaries: bnd[0]=0, bnd[s]=mids[s-1], bnd[nseg]=299

    float* rp = rawp[w];
    float* fp = fpad[w];
    int*   ps = pos[w];
    int*   bd = bnd[w];

    const float* rin = in + (size_t)row * FLEN;

    // ---- phase 1: coalesced load of the row into LDS (with zero pads) ----
    for (int i = lane; i < FLEN; i += 64) rp[3 + i] = rin[i];
    if (lane < 3) { rp[lane] = 0.f; rp[305 - lane] = 0.f; }
    if (lane == 0) { fp[0] = -INFINITY; fp[FLEN + 1] = -INFINITY; }
    __syncthreads();

    // ---- phase 2: 7-tap Gaussian blur, fp64 accumulate (fp32 coeffs) ----
    // chunked: lane l (<60) owns output indices [5l, 5l+5)
    if (lane < 60) {
        int base = lane * 5;
        #pragma unroll 1
        for (int j = 0; j < 5; ++j) {
            int i = base + j;
            double acc = bk0 * (double)rp[i]
                       + bk1 * (double)rp[i + 1]
                       + bk2 * (double)rp[i + 2]
                       + bk3 * (double)rp[i + 3]
                       + bk2 * (double)rp[i + 4]
                       + bk1 * (double)rp[i + 5]
                       + bk0 * (double)rp[i + 6];
            fp[1 + i] = (float)acc;
        }
    }
    __syncthreads();

    // ---- phase 3: strict peaks (with -inf boundary sentinels) + compaction ----
    int cnt = 0;
    unsigned pk = 0;
    if (lane < 60) {
        int base = lane * 5;
        #pragma unroll
        for (int j = 0; j < 5; ++j) {
            int i = base + j;
            float c = fp[1 + i];
            bool ispk = (c > fp[i]) && (c > fp[i + 2]);
            pk |= (unsigned)ispk << j;
            cnt += ispk;
        }
    }
    // wave-wide exclusive prefix sum of per-lane peak counts
    int incl = cnt;
    #pragma unroll
    for (int d = 1; d < 64; d <<= 1) {
        int v = __shfl_up(incl, d);
        if (lane >= d) incl += v;
    }
    int P   = __shfl(incl, 63);
    int off = incl - cnt;
    if (lane < 60) {
        int base = lane * 5;
        #pragma unroll
        for (int j = 0; j < 5; ++j)
            if ((pk >> j) & 1u) ps[off++] = base + j;
    }
    __syncthreads();

    const int nseg = (P > 0) ? P : 1;
    if (lane == 0) { bd[0] = 0; bd[nseg] = FLEN - 1; }
    for (int j = lane; j < P - 1; j += 64)
        bd[j + 1] = (ps[j] + ps[j + 1]) >> 1;   // floor midpoint divider
    __syncthreads();

    // ---- phase 4: per-segment stable softargmax over elements [0, 299) ----
    float sum_in = 0.f;
    int   any_in = 0;
    float m1 = -INFINITY, m2 = -INFINITY;   // top-2 of neg_sq among valid segments
    for (int s = lane; s < nseg; s += 64) {
        int lo = bd[s], hi = bd[s + 1];
        float mx = -INFINITY;
        for (int i = lo; i < hi; ++i) mx = fmaxf(mx, fp[1 + i]);
        float den = 0.f, num = 0.f;
        for (int i = lo; i < hi; ++i) {
            float e  = __expf(fp[1 + i] - mx);
            den += e;
            // freqs: exact fp32 op sequence ((i+1)-100)/100 * 2 - 1
            float fr = ((float)(i + 1 - 100) / 100.0f) * 2.0f - 1.0f;
            num = fmaf(e, fr, num);
        }
        float sm  = num / den;               // den >= 1 (segment nonempty)
        float nsq = -(sm * sm);
        bool  ii  = (sm > -1.0f) && (sm < 1.0f);
        if (ii) { sum_in += nsq; any_in = 1; }
        if (nsq > m1) { m2 = m1; m1 = nsq; } else { m2 = fmaxf(m2, nsq); }
    }

    // ---- wave butterfly reduction: sum, any, top-2 merge ----
    #pragma unroll
    for (int d = 32; d >= 1; d >>= 1) {
        sum_in += __shfl_xor(sum_in, d);
        any_in |= __shfl_xor(any_in, d);
        float o1 = __shfl_xor(m1, d);
        float o2 = __shfl_xor(m2, d);
        float n1 = fmaxf(m1, o1);
        float n2 = fmaxf(fminf(m1, o1), fmaxf(m2, o2));
        m1 = n1; m2 = n2;
    }

    if (lane == 0) {
        float t2 = m1 + ((m2 > -INFINITY) ? m2 : 0.0f);  // sum of finite top-2
        out[row] = any_in ? sum_in : t2;
    }
}

extern "C" void kernel_launch(void* const* d_in, const int* in_sizes, int n_in,
                              void* d_out, int out_size, void* d_ws, size_t ws_size,
                              hipStream_t stream) {
    const float* in  = (const float*)d_in[0];
    float*       out = (float*)d_out;
    const int B = in_sizes[0] / FLEN;          // 65536

    // Gaussian kernel, sigma=2, l=7: computed in double, rounded to fp32
    // (matching jnp.asarray(k/k.sum(), float32)), then widened back to double
    // for the fp64 accumulation on device.
    double k[7], s = 0.0;
    for (int t = 0; t < 7; ++t) {
        double x = -3.0 + (double)t;
        k[t] = exp(-0.5 * x * x / 4.0);
        s += k[t];
    }
    double bk0 = (double)(float)(k[0] / s);
    double bk1 = (double)(float)(k[1] / s);
    double bk2 = (double)(float)(k[2] / s);
    double bk3 = (double)(float)(k[3] / s);

    pil_kernel<<<B / RPB, 256, 0, stream>>>(in, out, bk0, bk1, bk2, bk3);
}